// Round 7
// baseline (146.431 us; speedup 1.0000x reference)
//
#include <hip/hip_runtime.h>
#include <math.h>

// Problem constants (from reference): B=2048, I=512, O=512
#define B_DIM 2048
#define I_DIM 512
#define O_DIM 512

constexpr int LANES   = 64;                    // threadIdx.x = one wave
constexpr int T_O     = 2;                     // o's per thread (keeps reg core at 64)
constexpr int O_BLK   = LANES * T_O;           // 128 o per block
constexpr int NWAVES  = 16;                    // waves per block = i-chunks (32 i each)
constexpr int R_BLOCK = 16;                    // rows per block (ab bytes/factor = 8/R)
constexpr int QPW     = (I_DIM / 4) / NWAVES;  // 8 i-quads per wave

// ---------------------------------------------------------------------------
// Setup kernel: precompute the affine ab table.
//   factor[b,i,o] = 1 - w*(1 - xnor) = a[i,o] + bcoef[i,o]*x[b,i]
//   a = 1 - w*s ; bcoef = w*(2s - 1)
// ab layout: float4 (a0,a1,b0,b1) at ab4[k*O_DIM+o], k = i/2.
// ---------------------------------------------------------------------------
__global__ __launch_bounds__(256) void setup_kernel(
    const float* __restrict__ w_logits,
    const float* __restrict__ s_logits,
    float4* __restrict__ ab4)
{
    int t  = blockIdx.x * 256 + threadIdx.x;  // 0 .. 131071
    int o  = t & (O_DIM - 1);
    int k  = t >> 9;                          // i-pair index, 0..255
    int i0 = 2 * k;

    float zw0 = w_logits[(i0 + 0) * O_DIM + o];
    float zs0 = s_logits[(i0 + 0) * O_DIM + o];
    float zw1 = w_logits[(i0 + 1) * O_DIM + o];
    float zs1 = s_logits[(i0 + 1) * O_DIM + o];

    float w0 = 1.0f / (1.0f + expf(-zw0));
    float s0 = 1.0f / (1.0f + expf(-zs0));
    float w1 = 1.0f / (1.0f + expf(-zw1));
    float s1 = 1.0f / (1.0f + expf(-zs1));

    float4 v;
    v.x = fmaf(-w0, s0, 1.0f);        // a0
    v.y = fmaf(-w1, s1, 1.0f);        // a1
    v.z = w0 * (2.0f * s0 - 1.0f);    // b0
    v.w = w1 * (2.0f * s1 - 1.0f);    // b1
    ab4[k * O_DIM + o] = v;
}

// ---------------------------------------------------------------------------
// Main product kernel. Block (64,16) = 16 waves = one full CU (4 waves/SIMD).
// threadIdx.y = i-chunk (32 i). Each thread: 16 b-rows x 2 o x 32 i.
// Grid 512 blocks (1-D): obase = (bid&3)*128, b-group = bid>>2.
//
// R6 post-mortem: R=8 @ 2 blocks/CU bought 4 waves/SIMD but DOUBLED ab
// traffic (ab bytes/factor = 8/R): L1 6.8->13.7us, L2 7.8->15.6us; overlap
// gains were eaten (dur 87.8->94.3). This version combines R=16 traffic
// (L1 6.8 / L2 7.8) WITH 4 waves/SIMD by making the 16-wave block itself
// the occupancy unit. T_O=2 shrinks the register core to acc[16][2]=32 +
// ab pipe 32 -> ~100 VGPR demand, under the 128 cap that
// __launch_bounds__(1024,1) implies (16 waves resident = 4/SIMD).
// Per-CU model: VALU 13.7 | LDS 10.2 | L1 6.8 | L2 7.8 -> overlapped ~16us.
// ---------------------------------------------------------------------------
__global__ __launch_bounds__(1024, 1) void fuzzy_main(
    const float* __restrict__ x,       // (B, I) fp32
    const float4* __restrict__ ab4,
    float* __restrict__ out)
{
    // 64 KB LDS, overlaid: x-tile (32 KB) during the product loop, then the
    // 8-buffer combine region (64 KB) after a barrier.
    __shared__ __align__(16) unsigned char sh_raw[8 * R_BLOCK * O_BLK * 4];
    float4 (*xs4)[I_DIM / 4] =
        reinterpret_cast<float4(*)[I_DIM / 4]>(sh_raw);                    // [16][128]
    float (*part)[R_BLOCK][O_BLK] =
        reinterpret_cast<float(*)[R_BLOCK][O_BLK]>(sh_raw);                // [8][16][128]

    const int lane  = threadIdx.x;                                      // 0..63
    const int y     = __builtin_amdgcn_readfirstlane((int)threadIdx.y); // 0..15
    const int tid   = y * LANES + lane;        // 0..1023
    const int bid   = blockIdx.x;              // 0..511
    const int obase = (bid & 3) * O_BLK;       // 4 o-blocks
    const int b0    = (bid >> 2) * R_BLOCK;    // 128 b-groups
    const int qbase = y * QPW;                 // first i-quad of this wave

    // Lane-varying base + uniform offsets -> saddr-form global loads.
    const float4* abp = ab4 + obase + lane;

    // Prime the 2-deep ab pipeline: set A = quad qbase, set B = qbase+1.
    // Quad q needs ab pair-rows 2q (i=4q..4q+1) and 2q+1 (i=4q+2..4q+3).
    float4 cA0[T_O], cA1[T_O], cB0[T_O], cB1[T_O];
#pragma unroll
    for (int j = 0; j < T_O; ++j) {
        cA0[j] = abp[(size_t)(2 * qbase + 0) * O_DIM + 64 * j];
        cA1[j] = abp[(size_t)(2 * qbase + 1) * O_DIM + 64 * j];
        cB0[j] = abp[(size_t)(2 * qbase + 2) * O_DIM + 64 * j];
        cB1[j] = abp[(size_t)(2 * qbase + 3) * O_DIM + 64 * j];
    }

    // Stage x tile: rows b0..b0+15 contiguous in global = 32 KB flat copy:
    // 2048 float4 / 1024 threads = 2 per thread, fully coalesced.
    {
        const float4* xsrc = (const float4*)x + (size_t)b0 * (I_DIM / 4);
        float4* xdst = (float4*)sh_raw;
#pragma unroll
        for (int p = 0; p < 2; ++p)
            xdst[p * 1024 + tid] = xsrc[p * 1024 + tid];
    }
    __syncthreads();

    float acc[R_BLOCK][T_O];
#pragma unroll
    for (int r = 0; r < R_BLOCK; ++r)
#pragma unroll
        for (int j = 0; j < T_O; ++j) acc[r][j] = 1.0f;

    for (int qq = 0; qq < QPW; qq += 2) {      // 4 iters, 2 quad-bodies each
        // ---- body A: quad qbase+qq ----
        {
            const int q = qbase + qq;
#pragma unroll
            for (int r = 0; r < R_BLOCK; ++r) {
                float4 xv = xs4[r][q];         // broadcast ds_read_b128
#pragma unroll
                for (int j = 0; j < T_O; ++j) {
                    float f0 = fmaf(cA0[j].z, xv.x, cA0[j].x);
                    float f1 = fmaf(cA0[j].w, xv.y, cA0[j].y);
                    float f2 = fmaf(cA1[j].z, xv.z, cA1[j].x);
                    float f3 = fmaf(cA1[j].w, xv.w, cA1[j].y);
                    acc[r][j] *= (f0 * f2) * (f1 * f3);
                }
            }
            // Refill set A for quad q+2 (consumed one full body later).
            // Final iters overrun ab4 by <=4 pair-rows (32 KB) -> ws slack.
#pragma unroll
            for (int j = 0; j < T_O; ++j) {
                cA0[j] = abp[(size_t)(2 * q + 4) * O_DIM + 64 * j];
                cA1[j] = abp[(size_t)(2 * q + 5) * O_DIM + 64 * j];
            }
        }
        // ---- body B: quad qbase+qq+1 ----
        {
            const int q = qbase + qq + 1;
#pragma unroll
            for (int r = 0; r < R_BLOCK; ++r) {
                float4 xv = xs4[r][q];
#pragma unroll
                for (int j = 0; j < T_O; ++j) {
                    float f0 = fmaf(cB0[j].z, xv.x, cB0[j].x);
                    float f1 = fmaf(cB0[j].w, xv.y, cB0[j].y);
                    float f2 = fmaf(cB1[j].z, xv.z, cB1[j].x);
                    float f3 = fmaf(cB1[j].w, xv.w, cB1[j].y);
                    acc[r][j] *= (f0 * f2) * (f1 * f3);
                }
            }
#pragma unroll
            for (int j = 0; j < T_O; ++j) {
                cB0[j] = abp[(size_t)(2 * q + 4) * O_DIM + 64 * j];
                cB1[j] = abp[(size_t)(2 * q + 5) * O_DIM + 64 * j];
            }
        }
    }

    // ---- combine the 16 i-chunk partials per (row, o) ----
    // part overlays xs4: barrier ensures all waves finished reading x.
    __syncthreads();
    // Phase 1: chunks 0..7 write their partials into the 8 buffers.
    if (y < 8) {
#pragma unroll
        for (int r = 0; r < R_BLOCK; ++r)
#pragma unroll
            for (int j = 0; j < T_O; ++j)
                part[y][r][64 * j + lane] = acc[r][j];
    }
    __syncthreads();
    // Phase 2: chunks 8..15 multiply into buffers 0..7 (1:1, race-free).
    if (y >= 8) {
#pragma unroll
        for (int r = 0; r < R_BLOCK; ++r)
#pragma unroll
            for (int j = 0; j < T_O; ++j)
                part[y - 8][r][64 * j + lane] *= acc[r][j];
    }
    __syncthreads();
    // Phase 3: fold the 8 buffers; 16 rows x 128 cols = 2048 outputs / 1024
    // threads = 2 each, lane-consecutive columns -> coalesced stores.
#pragma unroll
    for (int p = 0; p < 2; ++p) {
        int idx = p * 1024 + tid;                 // 0..2047
        int r = idx >> 7;                         // 0..15
        int c = idx & (O_BLK - 1);                // 0..127
        float v = ((part[0][r][c] * part[1][r][c])
                 * (part[2][r][c] * part[3][r][c]))
                * ((part[4][r][c] * part[5][r][c])
                 * (part[6][r][c] * part[7][r][c]));
        out[(size_t)(b0 + r) * O_DIM + obase + c] = v;
    }
}

extern "C" void kernel_launch(void* const* d_in, const int* in_sizes, int n_in,
                              void* d_out, int out_size, void* d_ws, size_t ws_size,
                              hipStream_t stream) {
    const float* x        = (const float*)d_in[0];   // (B, I) fp32
    const float* w_logits = (const float*)d_in[1];   // (I, O) fp32
    const float* s_logits = (const float*)d_in[2];   // (I, O) fp32
    float* out = (float*)d_out;                      // (B, O) fp32
    float4* ab4 = (float4*)d_ws;                     // [0, 2MB) + prefetch slack

    // Setup: ab table only (512 blocks).
    setup_kernel<<<dim3(512), dim3(256), 0, stream>>>(w_logits, s_logits, ab4);

    // Grid: 512 blocks (1-D): obase = (bid&3)*128, b-group = bid>>2.
    // (O/128)*(B/16) = 4*128 = 512 blocks of (64,16)=1024 threads.
    fuzzy_main<<<dim3(512), dim3(LANES, NWAVES), 0, stream>>>(
        x, ab4, out);
}

// Round 8
// 93.909 us; speedup vs baseline: 1.5593x; 1.5593x over previous
//
#include <hip/hip_runtime.h>
#include <math.h>

// Problem constants (from reference): B=2048, I=512, O=512
#define B_DIM 2048
#define I_DIM 512
#define O_DIM 512

constexpr int LANES   = 64;                    // threadIdx.x = one wave
constexpr int T_O     = 4;                     // o's per thread (T_O=4 required: LDS-pipe cost ~ 1/T_O)
constexpr int O_BLK   = LANES * T_O;           // 256 o per block
constexpr int NWAVES  = 8;                     // waves per block = disjoint i-chunks (64 i each)
constexpr int R_BLOCK = 8;                     // rows per block
constexpr int QPC     = (I_DIM / 4) / NWAVES;  // 16 i-quads per wave

// ---------------------------------------------------------------------------
// Setup kernel: precompute the affine ab table.
//   factor[b,i,o] = 1 - w*(1 - xnor) = a[i,o] + bcoef[i,o]*x[b,i]
//   a = 1 - w*s ; bcoef = w*(2s - 1)
// ab layout: float4 (a0,a1,b0,b1) at ab4[k*O_DIM+o], k = i/2.
// ---------------------------------------------------------------------------
__global__ __launch_bounds__(256) void setup_kernel(
    const float* __restrict__ w_logits,
    const float* __restrict__ s_logits,
    float4* __restrict__ ab4)
{
    int t  = blockIdx.x * 256 + threadIdx.x;  // 0 .. 131071
    int o  = t & (O_DIM - 1);
    int k  = t >> 9;                          // i-pair index, 0..255
    int i0 = 2 * k;

    float zw0 = w_logits[(i0 + 0) * O_DIM + o];
    float zs0 = s_logits[(i0 + 0) * O_DIM + o];
    float zw1 = w_logits[(i0 + 1) * O_DIM + o];
    float zs1 = s_logits[(i0 + 1) * O_DIM + o];

    float w0 = 1.0f / (1.0f + expf(-zw0));
    float s0 = 1.0f / (1.0f + expf(-zs0));
    float w1 = 1.0f / (1.0f + expf(-zw1));
    float s1 = 1.0f / (1.0f + expf(-zs1));

    float4 v;
    v.x = fmaf(-w0, s0, 1.0f);        // a0
    v.y = fmaf(-w1, s1, 1.0f);        // a1
    v.z = w0 * (2.0f * s0 - 1.0f);    // b0
    v.w = w1 * (2.0f * s1 - 1.0f);    // b1
    ab4[k * O_DIM + o] = v;
}

// ---------------------------------------------------------------------------
// Main product kernel. Block (64,8) = 8 waves, threadIdx.y = disjoint i-chunk
// (64 i). Each thread: 8 b-rows x 4 o x 64 i. Grid 512 blocks (1-D).
//
// R7 post-mortem (the rule that explains rounds 1-7): hipcc sets the VGPR
// budget from LDS-LIMITED MAX OCCUPANCY, ignoring launch_bounds arg2:
//   budget = 512 / (waves/SIMD at floor(160KB/LDS)*wavesPerBlock, cap 32/CU)
// 64KB+8w -> 16 w/CU -> 128 (R2/R3); 32KB -> 32 w/CU -> 64 (R5, and R6 --
// R6's 44us was a 64-VGPR spill, not an L1 wall); 64KB+16w -> 32 w/CU -> 64
// (R7, R1). So: LDS is PADDED to exactly 64 KB to force the 2-blocks/CU /
// 128-VGPR regime. Demand ~118 (acc 32 + ab dbuf 64 + temps) -> no spill,
// 4 waves/SIMD, 2-deep prefetch kept.
// T_O=4 kept: LDS-pipe cost ~ 1/T_O (reads = R*I/4 per block regardless of
// o-width); T_O=2 designs are LDS-bound (12cy/read > 7 VALU-cy/read share).
// obase=(bid&1): co-resident blocks n,n+256 share their ab slice -> L1
// ride-along halves L2 traffic.
// Per-CU model: VALU ~14us | LDS 10.2 | L1 7-14 | L2 ~8 -> overlapped 16-20.
// ---------------------------------------------------------------------------
__global__ __launch_bounds__(512, 2) void fuzzy_main(
    const float* __restrict__ x,       // (B, I) fp32
    const float4* __restrict__ ab4,
    float* __restrict__ out)
{
    // Exactly 64 KB LDS (occupancy control -- see header). Overlaid:
    // x-tile 16 KB during the product loop, 4-buffer combine 32 KB after.
    __shared__ __align__(16) unsigned char sh_raw[64 * 1024];
    float4 (*xs4)[I_DIM / 4] =
        reinterpret_cast<float4(*)[I_DIM / 4]>(sh_raw);                    // [8][128]
    float (*part)[R_BLOCK][O_BLK] =
        reinterpret_cast<float(*)[R_BLOCK][O_BLK]>(sh_raw);                // [4][8][256]

    const int lane  = threadIdx.x;                                      // 0..63
    const int y     = __builtin_amdgcn_readfirstlane((int)threadIdx.y); // 0..7, wave-uniform
    const int tid   = y * LANES + lane;        // 0..511
    const int bid   = blockIdx.x;              // 0..511
    const int obase = (bid & 1) * O_BLK;       // 2 o-blocks; n,n+256 share slice
    const int b0    = (bid >> 1) * R_BLOCK;    // 256 b-groups
    const int qbase = y * QPC;                 // first i-quad of this wave's chunk

    // Lane-varying base + uniform offsets -> saddr-form global loads.
    const float4* abp = ab4 + obase + lane;

    // Prime the 2-deep ab pipeline: set A = quad qbase, set B = qbase+1.
    // Quad q needs ab pair-rows 2q (i=4q..4q+1) and 2q+1 (i=4q+2..4q+3).
    float4 cA0[T_O], cA1[T_O], cB0[T_O], cB1[T_O];
#pragma unroll
    for (int j = 0; j < T_O; ++j) {
        cA0[j] = abp[(size_t)(2 * qbase + 0) * O_DIM + 64 * j];
        cA1[j] = abp[(size_t)(2 * qbase + 1) * O_DIM + 64 * j];
        cB0[j] = abp[(size_t)(2 * qbase + 2) * O_DIM + 64 * j];
        cB1[j] = abp[(size_t)(2 * qbase + 3) * O_DIM + 64 * j];
    }

    // Stage x tile: rows b0..b0+7 are contiguous in global (8 x 2 KB) = one
    // flat coalesced 16 KB copy: 1024 float4 / 512 threads = 2 per thread.
    {
        const float4* xsrc = (const float4*)x + (size_t)b0 * (I_DIM / 4);
        float4* xdst = (float4*)sh_raw;
#pragma unroll
        for (int p = 0; p < 2; ++p)
            xdst[p * 512 + tid] = xsrc[p * 512 + tid];
    }
    __syncthreads();

    float acc[R_BLOCK][T_O];
#pragma unroll
    for (int r = 0; r < R_BLOCK; ++r)
#pragma unroll
        for (int j = 0; j < T_O; ++j) acc[r][j] = 1.0f;

    for (int qq = 0; qq < QPC; qq += 2) {      // 8 iters, 2 quad-bodies each
        // ---- body A: quad qbase+qq ----
        {
            const int q = qbase + qq;
#pragma unroll
            for (int r = 0; r < R_BLOCK; ++r) {
                float4 xv = xs4[r][q];         // broadcast ds_read_b128
#pragma unroll
                for (int j = 0; j < T_O; ++j) {
                    float f0 = fmaf(cA0[j].z, xv.x, cA0[j].x);
                    float f1 = fmaf(cA0[j].w, xv.y, cA0[j].y);
                    float f2 = fmaf(cA1[j].z, xv.z, cA1[j].x);
                    float f3 = fmaf(cA1[j].w, xv.w, cA1[j].y);
                    acc[r][j] *= (f0 * f2) * (f1 * f3);
                }
            }
            // Refill set A for quad q+2 (consumed one full body later).
            // Final iters overrun ab4 by <=4 pair-rows (32 KB) -> ws slack.
#pragma unroll
            for (int j = 0; j < T_O; ++j) {
                cA0[j] = abp[(size_t)(2 * q + 4) * O_DIM + 64 * j];
                cA1[j] = abp[(size_t)(2 * q + 5) * O_DIM + 64 * j];
            }
        }
        // ---- body B: quad qbase+qq+1 ----
        {
            const int q = qbase + qq + 1;
#pragma unroll
            for (int r = 0; r < R_BLOCK; ++r) {
                float4 xv = xs4[r][q];
#pragma unroll
                for (int j = 0; j < T_O; ++j) {
                    float f0 = fmaf(cB0[j].z, xv.x, cB0[j].x);
                    float f1 = fmaf(cB0[j].w, xv.y, cB0[j].y);
                    float f2 = fmaf(cB1[j].z, xv.z, cB1[j].x);
                    float f3 = fmaf(cB1[j].w, xv.w, cB1[j].y);
                    acc[r][j] *= (f0 * f2) * (f1 * f3);
                }
            }
#pragma unroll
            for (int j = 0; j < T_O; ++j) {
                cB0[j] = abp[(size_t)(2 * q + 4) * O_DIM + 64 * j];
                cB1[j] = abp[(size_t)(2 * q + 5) * O_DIM + 64 * j];
            }
        }
    }

    // ---- combine the 8 i-chunk partials per (row, o) ----
    // part overlays xs4: barrier ensures all waves finished reading x.
    __syncthreads();
    // Phase 1: chunks 0..3 write their partials into the 4 buffers.
    if (y < 4) {
#pragma unroll
        for (int r = 0; r < R_BLOCK; ++r)
#pragma unroll
            for (int j = 0; j < T_O; ++j)
                part[y][r][64 * j + lane] = acc[r][j];
    }
    __syncthreads();
    // Phase 2: chunks 4..7 multiply into buffers 0..3 (1:1, race-free).
    if (y >= 4) {
#pragma unroll
        for (int r = 0; r < R_BLOCK; ++r)
#pragma unroll
            for (int j = 0; j < T_O; ++j)
                part[y - 4][r][64 * j + lane] *= acc[r][j];
    }
    __syncthreads();
    // Phase 3: fold the 4 buffers; 8 rows x 256 cols = 2048 outputs / 512
    // threads = 4 each, lane-consecutive columns -> coalesced stores.
#pragma unroll
    for (int p = 0; p < 4; ++p) {
        int idx = p * 512 + tid;                  // 0..2047
        int r = idx >> 8;                         // 0..7
        int c = idx & (O_BLK - 1);                // 0..255
        float v = part[0][r][c] * part[1][r][c]
                * part[2][r][c] * part[3][r][c];
        out[(size_t)(b0 + r) * O_DIM + obase + c] = v;
    }
}

extern "C" void kernel_launch(void* const* d_in, const int* in_sizes, int n_in,
                              void* d_out, int out_size, void* d_ws, size_t ws_size,
                              hipStream_t stream) {
    const float* x        = (const float*)d_in[0];   // (B, I) fp32
    const float* w_logits = (const float*)d_in[1];   // (I, O) fp32
    const float* s_logits = (const float*)d_in[2];   // (I, O) fp32
    float* out = (float*)d_out;                      // (B, O) fp32
    float4* ab4 = (float4*)d_ws;                     // [0, 2MB) + prefetch slack

    // Setup: ab table only (512 blocks).
    setup_kernel<<<dim3(512), dim3(256), 0, stream>>>(w_logits, s_logits, ab4);

    // Grid: 512 blocks (1-D): obase=(bid&1)*256, b-group=bid>>1.
    // (O/256)*(B/8) = 2*256 = 512 blocks of (64,8)=512 threads.
    fuzzy_main<<<dim3(512), dim3(LANES, NWAVES), 0, stream>>>(
        x, ab4, out);
}